// Round 5
// baseline (649.472 us; speedup 1.0000x reference)
//
#include <hip/hip_runtime.h>

// ---------------------------------------------------------------------------
// RingDilatedAttentionSDPA: B=1, S=8192, E=1024, H=16, D=64
// segments: (len=2048,dil=1), (4096,2), (8192->2048,4); mean of scattered outs
// Pipeline: cvt f32->bf16 ; QKV GEMM -> Q(pre-scaled log2e/8),K,V [h][s][d] ;
// transpose_v -> 3 sigma-permuted V^T dilation copies ; single flash launch
// (barrier-free K-loop: K/V MFMA fragments loaded DIRECTLY from global
// (L1/L2-served), LDS only for the P C->A relayout; exp2 softmax; l via
// ones-column MFMA) -> per-seg f32 buffers ; combine -> bf16 ; out GEMM.
// ---------------------------------------------------------------------------

typedef __attribute__((ext_vector_type(8))) short bf16x8;   // 8 bf16 in 4 VGPRs
typedef __attribute__((ext_vector_type(4))) float f32x4;

#define MFMA(a, b, c) __builtin_amdgcn_mfma_f32_16x16x32_bf16((a), (b), (c), 0, 0, 0)

#if __has_builtin(__builtin_amdgcn_exp2f)
#define EXP2(x) __builtin_amdgcn_exp2f(x)
#else
#define EXP2(x) exp2f(x)
#endif

static __device__ __forceinline__ unsigned short f2bf(float f) {
  unsigned int u = __float_as_uint(f);
  unsigned int r = (u + 0x7FFFu + ((u >> 16) & 1u)) >> 16;  // RNE
  return (unsigned short)r;
}

// ---------------------------- f32 -> bf16 convert --------------------------
__global__ void cvt_f32_bf16(const float* __restrict__ in,
                             unsigned short* __restrict__ out, int n8) {
  int i = blockIdx.x * blockDim.x + threadIdx.x;
  if (i >= n8) return;
  const float4* p = (const float4*)in + (size_t)i * 2;
  float4 a = p[0];
  float4 b = p[1];
  union { bf16x8 v; unsigned short u[8]; } o;
  o.u[0] = f2bf(a.x); o.u[1] = f2bf(a.y); o.u[2] = f2bf(a.z); o.u[3] = f2bf(a.w);
  o.u[4] = f2bf(b.x); o.u[5] = f2bf(b.y); o.u[6] = f2bf(b.z); o.u[7] = f2bf(b.w);
  *((bf16x8*)out + i) = o.v;
}

// ------------------------------- GEMM (C = A.B^T + bias) -------------------
// A: [M][K] bf16 row-major, B: [N][K] bf16 row-major. 128x128 tile, BK=32,
// 256 thr = 4 waves (2x2 of 64x64), 16x16x32 MFMA, global_load_lds width 16.
// EPILOGUE 0: qkv [3][16][8192][64] bf16, Q scaled by log2e/8; 1: f32 rowmaj.
template <int EPILOGUE>
__global__ __launch_bounds__(256, 2) void gemm_bt(
    const unsigned short* __restrict__ A, const unsigned short* __restrict__ B,
    const float* __restrict__ bias, void* __restrict__ Cout, int N, int K) {
  __shared__ unsigned short At[128 * 32];
  __shared__ unsigned short Bt[128 * 32];
  const int tid = threadIdx.x;
  const int wave = tid >> 6, lane = tid & 63;
  const int quad = lane >> 4, lc = lane & 15;
  const int wm = (wave >> 1) * 64, wn = (wave & 1) * 64;
  const int m0 = blockIdx.x * 128, n0 = blockIdx.y * 128;

  f32x4 acc[4][4] = {};

  for (int k0 = 0; k0 < K; k0 += 32) {
    __syncthreads();
#pragma unroll
    for (int issue = 0; issue < 2; ++issue) {
      const int cbase = issue * 256 + wave * 64;
      const int c = cbase + lane;
      const int row = c >> 2, col8 = (c & 3) * 8;   // 128 rows x 32 cols
      __builtin_amdgcn_global_load_lds(
          (const __attribute__((address_space(1))) void*)&A[(size_t)(m0 + row) * K + k0 + col8],
          (__attribute__((address_space(3))) void*)&At[cbase * 8], 16, 0, 0);
      __builtin_amdgcn_global_load_lds(
          (const __attribute__((address_space(1))) void*)&B[(size_t)(n0 + row) * K + k0 + col8],
          (__attribute__((address_space(3))) void*)&Bt[cbase * 8], 16, 0, 0);
    }
    __syncthreads();
    bf16x8 af[4], bfr[4];
#pragma unroll
    for (int t = 0; t < 4; ++t)
      af[t] = *(const bf16x8*)&At[(wm + t * 16 + lc) * 32 + quad * 8];
#pragma unroll
    for (int t = 0; t < 4; ++t)
      bfr[t] = *(const bf16x8*)&Bt[(wn + t * 16 + lc) * 32 + quad * 8];
#pragma unroll
    for (int i = 0; i < 4; ++i)
#pragma unroll
      for (int j = 0; j < 4; ++j)
        acc[i][j] = MFMA(af[i], bfr[j], acc[i][j]);
  }

#pragma unroll
  for (int i = 0; i < 4; ++i) {
#pragma unroll
    for (int j = 0; j < 4; ++j) {
      const int gcol = n0 + wn + j * 16 + lc;
      const float bs = bias[gcol];
#pragma unroll
      for (int r = 0; r < 4; ++r) {
        const int grow = m0 + wm + i * 16 + quad * 4 + r;
        const float v = acc[i][j][r] + bs;
        if (EPILOGUE == 0) {
          const int which = gcol >> 10, rem = gcol & 1023;
          const int hh = rem >> 6, d = rem & 63;
          // Q gets 1/sqrt(D) * log2(e) folded in (exp2 softmax downstream)
          const float vs = (which == 0) ? v * 0.18033688f : v;
          ((unsigned short*)Cout)[(((size_t)(which * 16 + hh)) * 8192 + grow) * 64 + d] = f2bf(vs);
        } else {
          ((float*)Cout)[(size_t)grow * N + gcol] = v;
        }
      }
    }
  }
}

// ---------------- V transpose: [h][s][d] -> sigma-permuted [h][d][n] -------
// sigma within each 64-block: pos = (n&15)*4 + (n>>4)  (matches P pi-pack)
__global__ void transpose_v(const unsigned short* __restrict__ v,
                            unsigned short* __restrict__ vt1,
                            unsigned short* __restrict__ vt2,
                            unsigned short* __restrict__ vt3) {
  __shared__ unsigned short Tt[64 * 72];
  const int tid = threadIdx.x;
  const int h = blockIdx.y;
  const int bx = blockIdx.x;
  const unsigned short* src = v + (size_t)h * 8192 * 64;
  unsigned short* dst;
  int dil, Nk, t0;
  if (bx < 32)      { dst = vt1; dil = 1; Nk = 2048; t0 = bx; }
  else if (bx < 96) { dst = vt2; dil = 2; Nk = 4096; t0 = bx - 32; }
  else              { dst = vt3; dil = 4; Nk = 2048; t0 = bx - 96; }
  dst += (size_t)h * 64 * Nk;
  const int j0 = t0 * 64;
#pragma unroll
  for (int it = 0; it < 2; ++it) {
    const int slot = tid + it * 256;
    const int jj = slot >> 3, c8 = (slot & 7) * 8;
    *(bf16x8*)&Tt[jj * 72 + c8] =
        *(const bf16x8*)&src[(size_t)(j0 + jj) * dil * 64 + c8];
  }
  __syncthreads();
  const int d = tid >> 2, pg = (tid & 3) * 16;
  union { bf16x8 v2[2]; unsigned short u[16]; } ob;
#pragma unroll
  for (int t = 0; t < 16; ++t) {
    const int pos = pg + t;
    const int jj = (pos & 3) * 16 + (pos >> 2);   // sigma^-1
    ob.u[t] = Tt[jj * 72 + d];
  }
  *(bf16x8*)&dst[(size_t)d * Nk + j0 + pg] = ob.v2[0];
  *(bf16x8*)&dst[(size_t)d * Nk + j0 + pg + 8] = ob.v2[1];
}

// --------------------------- flash attention, all segments -----------------
// qkvb: [3][16][8192][64] bf16 (Q pre-scaled log2e/8). vt*: [16][64][Nk],
// sigma-permuted per 64-block. blockIdx.z picks segment. WG = 128 q rows,
// 4 waves x 32 q. KV tile = 64 keys. BARRIER-FREE K-loop: K/V B-fragments
// are direct 16B/lane global loads (tiles hot in L1/L2); LDS only for the
// per-wave P C->A relayout. p = exp2(s); l via constant-ones-column MFMA.
__global__ __launch_bounds__(256, 4) void flash_all(
    const unsigned short* __restrict__ qkvb,
    const unsigned short* __restrict__ vt1, float* __restrict__ o1,
    const unsigned short* __restrict__ vt2, float* __restrict__ o2,
    const unsigned short* __restrict__ vt3, float* __restrict__ o3) {
  __shared__ unsigned short Pt[4][32 * 72];   // per-wave P tile [q][pos]

  const int z = blockIdx.z;
  const int Nk = (z == 1) ? 4096 : 2048;
  const int qt = blockIdx.x;
  if (qt * 128 >= Nk) return;                 // uniform early-out (seg1/3)
  const int dil = 1 << z;
  const unsigned short* vt = (z == 0) ? vt1 : (z == 1) ? vt2 : vt3;
  float* o = (z == 0) ? o1 : (z == 1) ? o2 : o3;

  const int tid = threadIdx.x;
  const int wave = tid >> 6, lane = tid & 63;
  const int quad = lane >> 4, lc = lane & 15;
  const int h = blockIdx.y;

  const unsigned short* qh = qkvb + (size_t)h * 8192 * 64;
  const unsigned short* kh = qkvb + (size_t)(16 + h) * 8192 * 64;
  const unsigned short* vh = vt + (size_t)h * 64 * Nk;

  // Q fragments: 2 m-blocks of 16 per wave (A[m=lc][k=quad*8+j (+32)])
  bf16x8 qf[2][2];
#pragma unroll
  for (int mb = 0; mb < 2; ++mb) {
    const int qrow = qt * 128 + wave * 32 + mb * 16 + lc;
    qf[mb][0] = *(const bf16x8*)&qh[(size_t)qrow * dil * 64 + quad * 8];
    qf[mb][1] = *(const bf16x8*)&qh[(size_t)qrow * dil * 64 + quad * 8 + 32];
  }

  // constant all-ones B fragment (bf16 1.0 = 0x3F80) for the row-sum MFMA
  union { bf16x8 v; unsigned short u[8]; } one_u;
#pragma unroll
  for (int t = 0; t < 8; ++t) one_u.u[t] = 0x3F80;
  const bf16x8 vone = one_u.v;

  f32x4 oacc[2][4] = {};
  f32x4 lacc[2] = {};

  // per-lane base addresses for direct K / V fragment loads
  const unsigned short* kbase = kh + (size_t)lc * dil * 64 + quad * 8;
  const unsigned short* vbase = vh + (size_t)lc * Nk + quad * 8;

  for (int kb = 0; kb < Nk; kb += 64) {
    // ---- S = Q.K^T : K B-frags direct from global [s][d] ----
    f32x4 sacc[2][4] = {};
#pragma unroll
    for (int jb = 0; jb < 4; ++jb) {
      const unsigned short* kr = kbase + (size_t)(kb + jb * 16) * dil * 64;
      const bf16x8 b0 = *(const bf16x8*)kr;
      const bf16x8 b1 = *(const bf16x8*)(kr + 32);
#pragma unroll
      for (int mb = 0; mb < 2; ++mb) {
        sacc[mb][jb] = MFMA(qf[mb][0], b0, sacc[mb][jb]);
        sacc[mb][jb] = MFMA(qf[mb][1], b1, sacc[mb][jb]);
      }
    }

    // p = exp2(s)
#pragma unroll
    for (int mb = 0; mb < 2; ++mb)
#pragma unroll
      for (int jb = 0; jb < 4; ++jb)
#pragma unroll
        for (int r = 0; r < 4; ++r) sacc[mb][jb][r] = EXP2(sacc[mb][jb][r]);

    // pack bf16 pairs, pi-order: keys {jb*16+lc} -> pos lc*4+jb
#pragma unroll
    for (int mb = 0; mb < 2; ++mb)
#pragma unroll
      for (int r = 0; r < 4; ++r) {
        const unsigned int a0 = __float_as_uint(sacc[mb][0][r]) + 0x8000u;
        const unsigned int a1 = __float_as_uint(sacc[mb][1][r]) + 0x8000u;
        const unsigned int a2 = __float_as_uint(sacc[mb][2][r]) + 0x8000u;
        const unsigned int a3 = __float_as_uint(sacc[mb][3][r]) + 0x8000u;
        uint2 w;
        w.x = __builtin_amdgcn_perm(a1, a0, 0x07060302u);
        w.y = __builtin_amdgcn_perm(a3, a2, 0x07060302u);
        *(uint2*)&Pt[wave][(mb * 16 + quad * 4 + r) * 72 + lc * 4] = w;
      }

    // P fragments (per-wave LDS; same-wave ds ordering via lgkmcnt)
    bf16x8 pf[2][2];
#pragma unroll
    for (int mb = 0; mb < 2; ++mb) {
      pf[mb][0] = *(const bf16x8*)&Pt[wave][(mb * 16 + lc) * 72 + quad * 8];
      pf[mb][1] = *(const bf16x8*)&Pt[wave][(mb * 16 + lc) * 72 + quad * 8 + 32];
    }

    // ---- O += P.V : V B-frags direct from global sigma-permuted [d][n] ----
#pragma unroll
    for (int nb = 0; nb < 4; ++nb) {
      const unsigned short* vr = vbase + (size_t)nb * 16 * Nk + kb;
      const bf16x8 v0 = *(const bf16x8*)vr;
      const bf16x8 v1 = *(const bf16x8*)(vr + 32);
#pragma unroll
      for (int mb = 0; mb < 2; ++mb) {
        oacc[mb][nb] = MFMA(pf[mb][0], v0, oacc[mb][nb]);
        oacc[mb][nb] = MFMA(pf[mb][1], v1, oacc[mb][nb]);
      }
    }
#pragma unroll
    for (int mb = 0; mb < 2; ++mb) {
      lacc[mb] = MFMA(pf[mb][0], vone, lacc[mb]);
      lacc[mb] = MFMA(pf[mb][1], vone, lacc[mb]);
    }
  }

#pragma unroll
  for (int mb = 0; mb < 2; ++mb)
#pragma unroll
    for (int r = 0; r < 4; ++r) {
      const int row = wave * 32 + mb * 16 + quad * 4 + r;
      const float inv = 1.0f / (3.0f * lacc[mb][r]);  // all lanes hold l
      const size_t base = (size_t)(qt * 128 + row) * 1024 + h * 64;
#pragma unroll
      for (int nb = 0; nb < 4; ++nb)
        o[base + nb * 16 + lc] = oacc[mb][nb][r] * inv;
    }
}

// ------------------- combine per-seg outputs -> bf16 a3 --------------------
__global__ void combine(const float* __restrict__ o1, const float* __restrict__ o2,
                        const float* __restrict__ o3,
                        unsigned short* __restrict__ a3b) {
  const int idx = blockIdx.x * 256 + threadIdx.x;   // 8192*128
  const int s = idx >> 7, e = (idx & 127) * 8;
  float acc[8] = {};
  if (s < 2048) {
    const float4* p = (const float4*)&o1[(size_t)s * 1024 + e];
#pragma unroll
    for (int t = 0; t < 4; ++t) { acc[t] += ((const float*)p)[t]; acc[4 + t] += ((const float*)p)[4 + t]; }
  }
  if (!(s & 1)) {
    const float4* p = (const float4*)&o2[(size_t)(s >> 1) * 1024 + e];
#pragma unroll
    for (int t = 0; t < 4; ++t) { acc[t] += ((const float*)p)[t]; acc[4 + t] += ((const float*)p)[4 + t]; }
  }
  if (!(s & 3)) {
    const float4* p = (const float4*)&o3[(size_t)(s >> 2) * 1024 + e];
#pragma unroll
    for (int t = 0; t < 4; ++t) { acc[t] += ((const float*)p)[t]; acc[4 + t] += ((const float*)p)[4 + t]; }
  }
  union { bf16x8 v; unsigned short u[8]; } ob;
#pragma unroll
  for (int t = 0; t < 8; ++t) ob.u[t] = f2bf(acc[t]);
  *(bf16x8*)&a3b[(size_t)s * 1024 + e] = ob.v;
}

// ---------------------------------------------------------------------------
extern "C" void kernel_launch(void* const* d_in, const int* in_sizes, int n_in,
                              void* d_out, int out_size, void* d_ws, size_t ws_size,
                              hipStream_t stream) {
  const float* x     = (const float*)d_in[0];  // [8192][1024]
  const float* w_qkv = (const float*)d_in[1];  // [3072][1024]
  const float* b_qkv = (const float*)d_in[2];  // [3072]
  const float* w_out = (const float*)d_in[3];  // [1024][1024]
  const float* b_out = (const float*)d_in[4];  // [1024]
  float* out = (float*)d_out;                  // [8192][1024] f32

  char* ws = (char*)d_ws;
  unsigned short* qkvb  = (unsigned short*)(ws);             // Q,K,V: 50,331,648 B
  // V third of qkvb (offset 33,554,432) doubles as o1/o3 after transpose_v:
  float*          o1    = (float*)(ws + 33554432);           //  8,388,608 B (over V)
  float*          o3    = (float*)(ws + 41943040);           //  8,388,608 B (over V)
  unsigned short* vt1   = (unsigned short*)(ws + 50331648);  //  4,194,304 B
  unsigned short* vt2   = (unsigned short*)(ws + 54525952);  //  8,388,608 B
  unsigned short* vt3   = (unsigned short*)(ws + 62914560);  //  4,194,304 B
  float*          o2    = (float*)(ws + 67108864);           // 16,777,216 B
  unsigned short* wqkvb = (unsigned short*)(ws + 83886080);  //  6,291,456 B
  unsigned short* woutb = (unsigned short*)(ws + 90177536);  //  2,097,152 B
  unsigned short* xb    = (unsigned short*)(ws + 92274688);  // 16,777,216 B (reused a3b)
  unsigned short* a3b   = xb;

  cvt_f32_bf16<<<dim3(8388608 / 8 / 256), dim3(256), 0, stream>>>(x, xb, 8388608 / 8);
  cvt_f32_bf16<<<dim3(3145728 / 8 / 256), dim3(256), 0, stream>>>(w_qkv, wqkvb, 3145728 / 8);
  cvt_f32_bf16<<<dim3(1048576 / 8 / 256), dim3(256), 0, stream>>>(w_out, woutb, 1048576 / 8);

  // QKV projection -> [3][16][8192][64] (Q pre-scaled by log2e/8)
  gemm_bt<0><<<dim3(64, 24), dim3(256), 0, stream>>>(xb, wqkvb, b_qkv, qkvb, 3072, 1024);

  // V -> sigma-permuted transposed dilation copies
  transpose_v<<<dim3(128, 16), dim3(256), 0, stream>>>(qkvb + (size_t)32 * 8192 * 64,
                                                       vt1, vt2, vt3);

  // all 3 attention segments in one launch (z: seg1 dil1, seg2 dil2, seg3 dil4)
  flash_all<<<dim3(32, 16, 3), dim3(256), 0, stream>>>(qkvb, vt1, o1, vt2, o2, vt3, o3);

  // sum segment outputs (mean /3 and /l already folded) -> bf16
  combine<<<dim3(4096), dim3(256), 0, stream>>>(o1, o2, o3, a3b);

  // output projection: out = a3 . woutb^T + b_out   (f32 out)
  gemm_bt<1><<<dim3(64, 8), dim3(256), 0, stream>>>(a3b, woutb, b_out, out, 1024, 1024);
}

// Round 6
// 340.998 us; speedup vs baseline: 1.9046x; 1.9046x over previous
//
#include <hip/hip_runtime.h>

// ---------------------------------------------------------------------------
// RingDilatedAttentionSDPA: B=1, S=8192, E=1024, H=16, D=64
// segments: (len=2048,dil=1), (4096,2), (8192->2048,4); mean of scattered outs
// Pipeline: cvt f32->bf16 ; QKV GEMM -> Q(pre-scaled log2e/8),K,V [h][s][d] ;
// transpose_v -> 3 key-permuted V^T dilation copies ; single flash launch
// computing S^T=K.Q^T and O^T=V^T.P^T (Q register-resident B-operand; packed
// exp2 C-regs ARE the P^T B-frag thanks to the vt key permutation — no P LDS
// round-trip; XOR-swizzled conflict-free LDS tiles) ; combine ; out GEMM.
// ---------------------------------------------------------------------------

typedef __attribute__((ext_vector_type(8))) short bf16x8;   // 8 bf16 in 4 VGPRs
typedef __attribute__((ext_vector_type(4))) float f32x4;

#define MFMA(a, b, c) __builtin_amdgcn_mfma_f32_16x16x32_bf16((a), (b), (c), 0, 0, 0)

#if __has_builtin(__builtin_amdgcn_exp2f)
#define EXP2(x) __builtin_amdgcn_exp2f(x)
#else
#define EXP2(x) exp2f(x)
#endif

static __device__ __forceinline__ unsigned short f2bf(float f) {
  unsigned int u = __float_as_uint(f);
  unsigned int r = (u + 0x7FFFu + ((u >> 16) & 1u)) >> 16;  // RNE
  return (unsigned short)r;
}

// ---------------------------- f32 -> bf16 convert --------------------------
__global__ void cvt_f32_bf16(const float* __restrict__ in,
                             unsigned short* __restrict__ out, int n8) {
  int i = blockIdx.x * blockDim.x + threadIdx.x;
  if (i >= n8) return;
  const float4* p = (const float4*)in + (size_t)i * 2;
  float4 a = p[0];
  float4 b = p[1];
  union { bf16x8 v; unsigned short u[8]; } o;
  o.u[0] = f2bf(a.x); o.u[1] = f2bf(a.y); o.u[2] = f2bf(a.z); o.u[3] = f2bf(a.w);
  o.u[4] = f2bf(b.x); o.u[5] = f2bf(b.y); o.u[6] = f2bf(b.z); o.u[7] = f2bf(b.w);
  *((bf16x8*)out + i) = o.v;
}

// ------------------------------- GEMM (C = A.B^T + bias) -------------------
// EPILOGUE 0: qkv [3][16][8192][64] bf16, Q scaled by log2e/8; 1: f32 rowmaj.
template <int EPILOGUE>
__global__ __launch_bounds__(256, 2) void gemm_bt(
    const unsigned short* __restrict__ A, const unsigned short* __restrict__ B,
    const float* __restrict__ bias, void* __restrict__ Cout, int N, int K) {
  __shared__ unsigned short At[128 * 32];
  __shared__ unsigned short Bt[128 * 32];
  const int tid = threadIdx.x;
  const int wave = tid >> 6, lane = tid & 63;
  const int quad = lane >> 4, lc = lane & 15;
  const int wm = (wave >> 1) * 64, wn = (wave & 1) * 64;
  const int m0 = blockIdx.x * 128, n0 = blockIdx.y * 128;

  f32x4 acc[4][4] = {};

  for (int k0 = 0; k0 < K; k0 += 32) {
    __syncthreads();
#pragma unroll
    for (int issue = 0; issue < 2; ++issue) {
      const int cbase = issue * 256 + wave * 64;
      const int c = cbase + lane;
      const int row = c >> 2, col8 = (c & 3) * 8;   // 128 rows x 32 cols
      __builtin_amdgcn_global_load_lds(
          (const __attribute__((address_space(1))) void*)&A[(size_t)(m0 + row) * K + k0 + col8],
          (__attribute__((address_space(3))) void*)&At[cbase * 8], 16, 0, 0);
      __builtin_amdgcn_global_load_lds(
          (const __attribute__((address_space(1))) void*)&B[(size_t)(n0 + row) * K + k0 + col8],
          (__attribute__((address_space(3))) void*)&Bt[cbase * 8], 16, 0, 0);
    }
    __syncthreads();
    bf16x8 af[4], bfr[4];
#pragma unroll
    for (int t = 0; t < 4; ++t)
      af[t] = *(const bf16x8*)&At[(wm + t * 16 + lc) * 32 + quad * 8];
#pragma unroll
    for (int t = 0; t < 4; ++t)
      bfr[t] = *(const bf16x8*)&Bt[(wn + t * 16 + lc) * 32 + quad * 8];
#pragma unroll
    for (int i = 0; i < 4; ++i)
#pragma unroll
      for (int j = 0; j < 4; ++j)
        acc[i][j] = MFMA(af[i], bfr[j], acc[i][j]);
  }

#pragma unroll
  for (int i = 0; i < 4; ++i) {
#pragma unroll
    for (int j = 0; j < 4; ++j) {
      const int gcol = n0 + wn + j * 16 + lc;
      const float bs = bias[gcol];
#pragma unroll
      for (int r = 0; r < 4; ++r) {
        const int grow = m0 + wm + i * 16 + quad * 4 + r;
        const float v = acc[i][j][r] + bs;
        if (EPILOGUE == 0) {
          const int which = gcol >> 10, rem = gcol & 1023;
          const int hh = rem >> 6, d = rem & 63;
          // Q gets 1/sqrt(D) * log2(e) folded in (exp2 softmax downstream)
          const float vs = (which == 0) ? v * 0.18033688f : v;
          ((unsigned short*)Cout)[(((size_t)(which * 16 + hh)) * 8192 + grow) * 64 + d] = f2bf(vs);
        } else {
          ((float*)Cout)[(size_t)grow * N + gcol] = v;
        }
      }
    }
  }
}

// ---------------- V transpose: [h][s][d] -> key-permuted [h][d][n] ---------
// perm within each 32-block: position p holds key 16*((p>>2)&1)+4*(p>>3)+(p&3)
// (matches the P^T B-fragment register order of the flash kernel).
__global__ void transpose_v(const unsigned short* __restrict__ v,
                            unsigned short* __restrict__ vt1,
                            unsigned short* __restrict__ vt2,
                            unsigned short* __restrict__ vt3) {
  __shared__ unsigned short Tt[64 * 72];
  const int tid = threadIdx.x;
  const int h = blockIdx.y;
  const int bx = blockIdx.x;
  const unsigned short* src = v + (size_t)h * 8192 * 64;
  unsigned short* dst;
  int dil, Nk, t0;
  if (bx < 32)      { dst = vt1; dil = 1; Nk = 2048; t0 = bx; }
  else if (bx < 96) { dst = vt2; dil = 2; Nk = 4096; t0 = bx - 32; }
  else              { dst = vt3; dil = 4; Nk = 2048; t0 = bx - 96; }
  dst += (size_t)h * 64 * Nk;
  const int j0 = t0 * 64;
#pragma unroll
  for (int it = 0; it < 2; ++it) {
    const int slot = tid + it * 256;
    const int jj = slot >> 3, c8 = (slot & 7) * 8;
    *(bf16x8*)&Tt[jj * 72 + c8] =
        *(const bf16x8*)&src[(size_t)(j0 + jj) * dil * 64 + c8];
  }
  __syncthreads();
  const int d = tid >> 2, pg = (tid & 3) * 16;
  union { bf16x8 v2[2]; unsigned short u[16]; } ob;
#pragma unroll
  for (int t = 0; t < 16; ++t) {
    const int pos = pg + t;
    const int w = pos & 31;
    const int jj = (pos & 32) | (((w >> 2) & 1) * 16 + (w >> 3) * 4 + (w & 3));
    ob.u[t] = Tt[jj * 72 + d];
  }
  *(bf16x8*)&dst[(size_t)d * Nk + j0 + pg] = ob.v2[0];
  *(bf16x8*)&dst[(size_t)d * Nk + j0 + pg + 8] = ob.v2[1];
}

// --------------------------- flash attention, all segments -----------------
// S^T = K.Q^T (A=K from LDS, B=Q register-resident); O^T = V^T.P^T (A=V^T
// from LDS, B=P^T built in-register from packed exp2 C-regs — key perm in vt
// makes the layouts coincide). WG = 256 q (4 waves x 64 q), KV tile = 64 keys.
// LDS: K tile + V^T tile, XOR-swizzled 16B chunks (chunk^ = c ^ (row&7)) ->
// conflict-free b128; same 16KB reused for the O^T->O epilogue transpose.
// l via ones-A-frag MFMA. Block mapping: even bx = seg2, odd bx = seg1/3.
__global__ __launch_bounds__(256, 2) void flash_all(
    const unsigned short* __restrict__ qkvb,
    const unsigned short* __restrict__ vt1, float* __restrict__ o1,
    const unsigned short* __restrict__ vt2, float* __restrict__ o2,
    const unsigned short* __restrict__ vt3, float* __restrict__ o3) {
  __shared__ unsigned short Smem[2 * 64 * 64];  // Kt | Vt ; epilogue: f32 O^T
  unsigned short* Kt = Smem;
  unsigned short* Vt = Smem + 64 * 64;

  // block -> (segment, head, q-tile): even bx = seg2; odd alternates seg1/seg3
  const int bx = blockIdx.x;
  int z, h, qt;
  if ((bx & 1) == 0) { const int i = bx >> 1; z = 1; h = i >> 4; qt = i & 15; }
  else { const int j = bx >> 1; z = (j & 1) ? 2 : 0; const int i = j >> 1; h = i >> 3; qt = i & 7; }
  const int Nk = (z == 1) ? 4096 : 2048;
  const int dil = 1 << z;
  const unsigned short* vt = (z == 0) ? vt1 : (z == 1) ? vt2 : vt3;
  float* o = (z == 0) ? o1 : (z == 1) ? o2 : o3;

  const int tid = threadIdx.x;
  const int wave = tid >> 6, lane = tid & 63;
  const int quad = lane >> 4, lc = lane & 15;

  const unsigned short* qh = qkvb + (size_t)h * 8192 * 64;
  const unsigned short* kh = qkvb + (size_t)(16 + h) * 8192 * 64;
  const unsigned short* vh = vt + (size_t)h * 64 * Nk;

  // Q B-fragments: 4 m-blocks of 16 q (B[n=lc][k=quad*8+j], halves d<32,>=32)
  bf16x8 qf[4][2];
#pragma unroll
  for (int mb = 0; mb < 4; ++mb) {
    const size_t qrow = (size_t)(qt * 256 + wave * 64 + mb * 16 + lc) * dil;
    qf[mb][0] = *(const bf16x8*)&qh[qrow * 64 + quad * 8];
    qf[mb][1] = *(const bf16x8*)&qh[qrow * 64 + quad * 8 + 32];
  }

  // constant all-ones A fragment (bf16 1.0) for the row-sum (l) MFMA
  union { bf16x8 v; unsigned short u[8]; } one_u;
#pragma unroll
  for (int t = 0; t < 8; ++t) one_u.u[t] = 0x3F80;
  const bf16x8 vone = one_u.v;

  f32x4 oacc[4][4] = {};   // [mb][nb]  O^T C-tiles: row=d, col=q
  f32x4 lacc[4] = {};      // [mb]      l per q (all rows identical)

  // staging: 512 slots of 16B per tile-pair; swizzled chunk = scol ^ (row&7)
  const int srow = tid >> 3, scol = tid & 7;
  const int swz = (scol ^ (srow & 7)) * 8;

  bf16x8 kg0 = *(const bf16x8*)&kh[(size_t)(srow * dil) * 64 + scol * 8];
  bf16x8 kg1 = *(const bf16x8*)&kh[(size_t)((srow + 32) * dil) * 64 + scol * 8];
  bf16x8 vg0 = *(const bf16x8*)&vh[(size_t)srow * Nk + scol * 8];
  bf16x8 vg1 = *(const bf16x8*)&vh[(size_t)(srow + 32) * Nk + scol * 8];

  for (int kb = 0; kb < Nk; kb += 64) {
    __syncthreads();
    *(bf16x8*)&Kt[srow * 64 + swz] = kg0;
    *(bf16x8*)&Kt[(srow + 32) * 64 + swz] = kg1;
    *(bf16x8*)&Vt[srow * 64 + swz] = vg0;
    *(bf16x8*)&Vt[(srow + 32) * 64 + swz] = vg1;
    __syncthreads();

    if (kb + 64 < Nk) {   // prefetch next tile into registers
      const int nk = kb + 64;
      kg0 = *(const bf16x8*)&kh[(size_t)((nk + srow) * dil) * 64 + scol * 8];
      kg1 = *(const bf16x8*)&kh[(size_t)((nk + srow + 32) * dil) * 64 + scol * 8];
      vg0 = *(const bf16x8*)&vh[(size_t)srow * Nk + nk + scol * 8];
      vg1 = *(const bf16x8*)&vh[(size_t)(srow + 32) * Nk + nk + scol * 8];
    }

#pragma unroll
    for (int ks = 0; ks < 2; ++ks) {         // two 32-key subsets
      // ---- S^T tiles: D[m=key][n=q] = K.Q^T ----
      f32x4 st[2][4];
#pragma unroll
      for (int t = 0; t < 2; ++t) {
        const int row = (ks * 2 + t) * 16 + lc;
        const bf16x8 ka0 = *(const bf16x8*)&Kt[row * 64 + ((quad ^ (lc & 7)) * 8)];
        const bf16x8 ka1 = *(const bf16x8*)&Kt[row * 64 + (((4 + quad) ^ (lc & 7)) * 8)];
#pragma unroll
        for (int mb = 0; mb < 4; ++mb) {
          f32x4 zz = {};
          zz = MFMA(ka0, qf[mb][0], zz);
          st[t][mb] = MFMA(ka1, qf[mb][1], zz);
        }
      }

      // ---- p = exp2(s); pack -> P^T B-frags (register order == vt key perm)
      bf16x8 pb[4];
#pragma unroll
      for (int mb = 0; mb < 4; ++mb) {
        union { bf16x8 v; unsigned int u[4]; } pu;
#pragma unroll
        for (int t = 0; t < 2; ++t) {
          const unsigned int a0 = __float_as_uint(EXP2(st[t][mb][0])) + 0x8000u;
          const unsigned int a1 = __float_as_uint(EXP2(st[t][mb][1])) + 0x8000u;
          const unsigned int a2 = __float_as_uint(EXP2(st[t][mb][2])) + 0x8000u;
          const unsigned int a3 = __float_as_uint(EXP2(st[t][mb][3])) + 0x8000u;
          pu.u[t * 2 + 0] = __builtin_amdgcn_perm(a1, a0, 0x07060302u);
          pu.u[t * 2 + 1] = __builtin_amdgcn_perm(a3, a2, 0x07060302u);
        }
        pb[mb] = pu.v;
      }

      // ---- O^T += V^T.P^T ; l += 1.P^T ----
#pragma unroll
      for (int nb = 0; nb < 4; ++nb) {
        const int vrow = nb * 16 + lc;
        const bf16x8 va = *(const bf16x8*)&Vt[vrow * 64 + (((ks * 4 + quad) ^ (lc & 7)) * 8)];
#pragma unroll
        for (int mb = 0; mb < 4; ++mb)
          oacc[mb][nb] = MFMA(va, pb[mb], oacc[mb][nb]);
      }
#pragma unroll
      for (int mb = 0; mb < 4; ++mb) lacc[mb] = MFMA(vone, pb[mb], lacc[mb]);
    }
  }

  // ---- epilogue: O^T -> O via swizzled LDS transpose, coalesced stores ----
  __syncthreads();                       // all waves done reading Kt/Vt
  float* W = (float*)Smem + wave * 16 * 64;   // per-wave 16q x 64d region
  const int g = lane >> 2, s4 = lane & 3;
#pragma unroll
  for (int mb = 0; mb < 4; ++mb) {
    const float inv = 1.0f / (3.0f * lacc[mb][0]);   // fold mean over 3 segs
#pragma unroll
    for (int nb = 0; nb < 4; ++nb) {
      const int c = nb * 4 + quad;
      const int cs = (c & 8) | ((c & 7) ^ (lc & 7));
      f32x4 val = oacc[mb][nb];
      val *= inv;
      *(f32x4*)&W[lc * 64 + cs * 4] = val;
    }
    // read back transposed (same-wave ds ordering via lgkmcnt)
    const size_t base = (size_t)(qt * 256 + wave * 64 + mb * 16 + g) * 1024 +
                        (size_t)((bx & 1) ? ((bx >> 1) >> 1) >> 3 : (bx >> 1) >> 4) * 64 + s4 * 16;
#pragma unroll
    for (int c2 = 0; c2 < 4; ++c2) {
      const int c = s4 * 4 + c2;
      const int cs = (c & 8) | ((c & 7) ^ (g & 7));
      *(float4*)&o[base + c2 * 4] = *(const float4*)&W[g * 64 + cs * 4];
    }
  }
}

// ------------------- combine per-seg outputs -> bf16 a3 --------------------
__global__ void combine(const float* __restrict__ o1, const float* __restrict__ o2,
                        const float* __restrict__ o3,
                        unsigned short* __restrict__ a3b) {
  const int idx = blockIdx.x * 256 + threadIdx.x;   // 8192*128
  const int s = idx >> 7, e = (idx & 127) * 8;
  float acc[8] = {};
  if (s < 2048) {
    const float* p = &o1[(size_t)s * 1024 + e];
#pragma unroll
    for (int t = 0; t < 8; ++t) acc[t] += p[t];
  }
  if (!(s & 1)) {
    const float* p = &o2[(size_t)(s >> 1) * 1024 + e];
#pragma unroll
    for (int t = 0; t < 8; ++t) acc[t] += p[t];
  }
  if (!(s & 3)) {
    const float* p = &o3[(size_t)(s >> 2) * 1024 + e];
#pragma unroll
    for (int t = 0; t < 8; ++t) acc[t] += p[t];
  }
  union { bf16x8 v; unsigned short u[8]; } ob;
#pragma unroll
  for (int t = 0; t < 8; ++t) ob.u[t] = f2bf(acc[t]);
  *(bf16x8*)&a3b[(size_t)s * 1024 + e] = ob.v;
}

// ---------------------------------------------------------------------------
extern "C" void kernel_launch(void* const* d_in, const int* in_sizes, int n_in,
                              void* d_out, int out_size, void* d_ws, size_t ws_size,
                              hipStream_t stream) {
  const float* x     = (const float*)d_in[0];  // [8192][1024]
  const float* w_qkv = (const float*)d_in[1];  // [3072][1024]
  const float* b_qkv = (const float*)d_in[2];  // [3072]
  const float* w_out = (const float*)d_in[3];  // [1024][1024]
  const float* b_out = (const float*)d_in[4];  // [1024]
  float* out = (float*)d_out;                  // [8192][1024] f32

  char* ws = (char*)d_ws;
  unsigned short* qkvb  = (unsigned short*)(ws);             // Q,K,V: 50,331,648 B
  // V third of qkvb (offset 33,554,432) doubles as o1/o3 after transpose_v:
  float*          o1    = (float*)(ws + 33554432);           //  8,388,608 B (over V)
  float*          o3    = (float*)(ws + 41943040);           //  8,388,608 B (over V)
  unsigned short* vt1   = (unsigned short*)(ws + 50331648);  //  4,194,304 B
  unsigned short* vt2   = (unsigned short*)(ws + 54525952);  //  8,388,608 B
  unsigned short* vt3   = (unsigned short*)(ws + 62914560);  //  4,194,304 B
  float*          o2    = (float*)(ws + 67108864);           // 16,777,216 B
  unsigned short* wqkvb = (unsigned short*)(ws + 83886080);  //  6,291,456 B
  unsigned short* woutb = (unsigned short*)(ws + 90177536);  //  2,097,152 B
  unsigned short* xb    = (unsigned short*)(ws + 92274688);  // 16,777,216 B (reused a3b)
  unsigned short* a3b   = xb;

  cvt_f32_bf16<<<dim3(8388608 / 8 / 256), dim3(256), 0, stream>>>(x, xb, 8388608 / 8);
  cvt_f32_bf16<<<dim3(3145728 / 8 / 256), dim3(256), 0, stream>>>(w_qkv, wqkvb, 3145728 / 8);
  cvt_f32_bf16<<<dim3(1048576 / 8 / 256), dim3(256), 0, stream>>>(w_out, woutb, 1048576 / 8);

  // QKV projection -> [3][16][8192][64] (Q pre-scaled by log2e/8)
  gemm_bt<0><<<dim3(64, 24), dim3(256), 0, stream>>>(xb, wqkvb, b_qkv, qkvb, 3072, 1024);

  // V -> key-permuted transposed dilation copies
  transpose_v<<<dim3(128, 16), dim3(256), 0, stream>>>(qkvb + (size_t)32 * 8192 * 64,
                                                       vt1, vt2, vt3);

  // all 3 attention segments, balanced 512-block launch (2 blocks/CU)
  flash_all<<<dim3(512), dim3(256), 0, stream>>>(qkvb, vt1, o1, vt2, o2, vt3, o3);

  // sum segment outputs (mean /3 and /l already folded) -> bf16
  combine<<<dim3(4096), dim3(256), 0, stream>>>(o1, o2, o3, a3b);

  // output projection: out = a3 . woutb^T + b_out   (f32 out)
  gemm_bt<1><<<dim3(64, 8), dim3(256), 0, stream>>>(a3b, woutb, b_out, out, 1024, 1024);
}